// Round 5
// baseline (121.578 us; speedup 1.0000x reference)
//
#include <hip/hip_runtime.h>
#include <hip/hip_bf16.h>
#include <math.h>

#define HW   4096
#define NC   64
#define NB   2
#define NHD  4
#define DH   16
#define NBH  (NB*NHD)

typedef __attribute__((ext_vector_type(4))) float f32x4;
typedef __attribute__((ext_vector_type(8))) short bf16x8;
typedef __attribute__((ext_vector_type(2))) unsigned int uint2v;

#define QSCALE 0.36067376022224087f   // 0.25 * log2(e)

static __device__ __forceinline__ unsigned short bf16_bits(float f) {
    union { __hip_bfloat16 h; unsigned short u; } cv;
    cv.h = __float2bfloat16(f);
    return cv.u;
}
static __device__ __forceinline__ float bits_to_f(unsigned short b) {
    return __uint_as_float(((unsigned int)b) << 16);
}
static __device__ __forceinline__ unsigned int cvt_pk_bf16(float lo, float hi) {
    unsigned int r;
    asm("v_cvt_pk_bf16_f32 %0, %1, %2" : "=v"(r) : "v"(lo), "v"(hi));
    return r;
}

// ---------------------------------------------------------------------------
// Kernel A: qkv + illu 1x1 convs. 1024 blocks x 192 thr, 8 pixels/block.
// Q (pre-scaled 0.25*log2e) and K (=k+illu) stored DOUBLE-BF16 [bh][p][32]
// (d0-15 hi, d16-31 lo). V single bf16 transposed: Vt [bh][d][key].
// ---------------------------------------------------------------------------
__global__ __launch_bounds__(192) void qkv_kernel(
    const float* __restrict__ x, const float* __restrict__ illu,
    const float* __restrict__ qkv_w, const float* __restrict__ qkv_b,
    const float* __restrict__ illu_w, const float* __restrict__ illu_b,
    ushort* __restrict__ Qx, ushort* __restrict__ Kx, ushort* __restrict__ Vt)
{
    const int PIX = 8;
    __shared__ float xs[PIX][NC];
    __shared__ float fs[PIX][NC];
    __shared__ ushort vs[NC][PIX];
    int blk = blockIdx.x;                // 1024
    int b   = blk >> 9;
    int p0  = (blk & 511) * PIX;
    int tid = threadIdx.x;

    for (int idx = tid; idx < PIX*NC; idx += 192) {
        int ch = idx >> 3;
        int pp = idx & 7;
        xs[pp][ch] = x   [(b*NC + ch)*HW + p0 + pp];
        fs[pp][ch] = illu[(b*NC + ch)*HW + p0 + pp];
    }

    int role = tid / 64;                 // 0=q 1=k 2=v
    int co   = tid & 63;                 // head*16 + dd
    int head = co >> 4;
    int dd   = co & 15;
    int bh   = b*NHD + head;

    float wq[NC];
    #pragma unroll
    for (int c4 = 0; c4 < NC/4; c4++) {
        float4 w = ((const float4*)(qkv_w + tid*NC))[c4];
        wq[4*c4+0] = w.x; wq[4*c4+1] = w.y; wq[4*c4+2] = w.z; wq[4*c4+3] = w.w;
    }
    float bias = qkv_b[tid];
    float wi[NC];
    if (role == 1) {
        #pragma unroll
        for (int c4 = 0; c4 < NC/4; c4++) {
            float4 w = ((const float4*)(illu_w + co*NC))[c4];
            wi[4*c4+0] = w.x; wi[4*c4+1] = w.y; wi[4*c4+2] = w.z; wi[4*c4+3] = w.w;
        }
        bias += illu_b[co];
    }
    __syncthreads();

    #pragma unroll
    for (int pp = 0; pp < PIX; pp++) {
        float a0 = 0.f, a1 = 0.f, a2 = 0.f, a3 = 0.f;
        #pragma unroll
        for (int c4 = 0; c4 < NC/4; c4++) {
            float4 xv = ((const float4*)xs[pp])[c4];
            a0 = fmaf(wq[4*c4+0], xv.x, a0);
            a1 = fmaf(wq[4*c4+1], xv.y, a1);
            a2 = fmaf(wq[4*c4+2], xv.z, a2);
            a3 = fmaf(wq[4*c4+3], xv.w, a3);
        }
        float acc = bias + ((a0 + a1) + (a2 + a3));
        if (role == 1) {
            float b0 = 0.f, b1 = 0.f, b2 = 0.f, b3 = 0.f;
            #pragma unroll
            for (int c4 = 0; c4 < NC/4; c4++) {
                float4 iv = ((const float4*)fs[pp])[c4];
                b0 = fmaf(wi[4*c4+0], iv.x, b0);
                b1 = fmaf(wi[4*c4+1], iv.y, b1);
                b2 = fmaf(wi[4*c4+2], iv.z, b2);
                b3 = fmaf(wi[4*c4+3], iv.w, b3);
            }
            acc += ((b0 + b1) + (b2 + b3));
        }
        size_t pidx = (size_t)bh*HW*32 + (size_t)(p0+pp)*32 + dd;
        if (role == 0) {
            float v = acc * QSCALE;
            unsigned short hb = bf16_bits(v);
            Qx[pidx]      = hb;
            Qx[pidx + 16] = bf16_bits(v - bits_to_f(hb));
        } else if (role == 1) {
            unsigned short hb = bf16_bits(acc);
            Kx[pidx]      = hb;
            Kx[pidx + 16] = bf16_bits(acc - bits_to_f(hb));
        } else {
            vs[co][pp] = bf16_bits(acc);
        }
    }
    __syncthreads();
    for (int idx = tid; idx < NC*PIX/2; idx += 192) {
        int row = idx >> 2;              // co
        int j   = idx & 3;
        unsigned int val = *(const unsigned int*)&vs[row][2*j];
        ((unsigned int*)(Vt + ((size_t)(b*NC + row))*HW + p0))[j] = val;
    }
}

// ---------------------------------------------------------------------------
// Kernel B: MFMA flash attention. 1024 blocks x 128 thr (2 waves, 32 q-rows).
// Builtin MFMA (compiler-modeled: hazards/waitcnts handled).
// Swapped QK^T: mfma(K,Q), K double-bf16 in A slots (hi|lo), B1=[Qhi|Qhi],
// B2=[Qlo|Qlo] -> exact (Khi+Klo)(Qhi+Qlo). P single bf16 via v_cvt_pk;
// l summed from raw fp32 p. No-max softmax (logits bounded => exact).
// ---------------------------------------------------------------------------
#define KT 128

__global__ __launch_bounds__(128) void attn_kernel(
    const ushort* __restrict__ Qx, const ushort* __restrict__ Kx,
    const ushort* __restrict__ Vt, float* __restrict__ O)
{
    __shared__ alignas(16) ushort Ks[128*32];   // [row][slot*8] XOR-swizzled, 8KB
    __shared__ alignas(16) ushort Vs[16*136];   // [d][136 pad]  4.25KB

    int blk  = blockIdx.x;               // 1024
    int bh   = blk >> 7;
    int q0   = (blk & 127) * 32;
    int tid  = threadIdx.x;              // 0..127
    int w    = tid >> 6;                 // 0..1
    int lane = tid & 63;
    int g    = lane >> 4;                // lane group 0..3
    int qc   = lane & 15;                // query col / A-row / V d-col

    const ushort* Qb = Qx + (size_t)bh*HW*32;
    const ushort* Kb = Kx + (size_t)bh*HW*32;
    const ushort* Vb = Vt + (size_t)bh*DH*HW;

    int qrow = q0 + w*16 + qc;
    bf16x8 qhi = *(const bf16x8*)(Qb + (size_t)qrow*32 +      8*(g&1));
    bf16x8 qlo = *(const bf16x8*)(Qb + (size_t)qrow*32 + 16 + 8*(g&1));

    f32x4 zero4 = {0.f, 0.f, 0.f, 0.f};
    f32x4 oacc  = {0.f, 0.f, 0.f, 0.f};
    f32x4 lacc  = {0.f, 0.f, 0.f, 0.f};

    // lane-constant pieces: m = (krow&3)^((krow>>2)&3) depends only on qc
    int mconst = (qc & 3) ^ ((qc >> 2) & 3);
    const ushort* kread = Ks + qc*32 + ((g ^ mconst)*8);
    const ushort* vread = Vs + qc*136 + 4*g;

    for (int t = 0; t < HW/KT; ++t) {
        __syncthreads();
        int kt = t * KT;
        // stage K tile: 128 rows x 32 (hi|lo) = 512 16B-chunks, 4 per thread
        #pragma unroll
        for (int j = 0; j < 4; ++j) {
            int f = tid + j*128;
            int r = f >> 2, h = f & 3;
            int m = (r & 3) ^ ((r >> 2) & 3);
            bf16x8 kv = *(const bf16x8*)(Kb + (size_t)(kt + r)*32 + 8*h);
            *(bf16x8*)(Ks + r*32 + (h ^ m)*8) = kv;
        }
        // stage V^T tile: 16 d-rows x 128 keys = 256 chunks, 2 per thread
        #pragma unroll
        for (int j = 0; j < 2; ++j) {
            int f = tid + j*128;
            int d = f >> 4, seg = f & 15;
            bf16x8 vv = *(const bf16x8*)(Vb + (size_t)d*HW + kt + seg*8);
            *(bf16x8*)(Vs + d*136 + seg*8) = vv;
        }
        __syncthreads();

        unsigned int pe0 = 0, pe1 = 0;
        #pragma unroll
        for (int kb = 0; kb < 8; ++kb) {
            bf16x8 kfrag = *(const bf16x8*)(kread + kb*512);
            f32x4 s = __builtin_amdgcn_mfma_f32_16x16x32_bf16(kfrag, qhi, zero4, 0, 0, 0);
            s = __builtin_amdgcn_mfma_f32_16x16x32_bf16(kfrag, qlo, s, 0, 0, 0);
            float p0 = __builtin_amdgcn_exp2f(s.x);
            float p1 = __builtin_amdgcn_exp2f(s.y);
            float p2 = __builtin_amdgcn_exp2f(s.z);
            float p3 = __builtin_amdgcn_exp2f(s.w);
            lacc.x += p0; lacc.y += p1; lacc.z += p2; lacc.w += p3;
            unsigned int plo = cvt_pk_bf16(p0, p1);
            unsigned int phi = cvt_pk_bf16(p2, p3);
            if ((kb & 1) == 0) { pe0 = plo; pe1 = phi; }
            else {
                uint2v vE = *(const uint2v*)(vread + (kb-1)*16);
                uint2v vO = *(const uint2v*)(vread + kb*16);
                union { unsigned int u[4]; bf16x8 h; } pa, vb;
                pa.u[0] = pe0;  pa.u[1] = pe1;  pa.u[2] = plo;  pa.u[3] = phi;
                vb.u[0] = vE.x; vb.u[1] = vE.y; vb.u[2] = vO.x; vb.u[3] = vO.y;
                oacc = __builtin_amdgcn_mfma_f32_16x16x32_bf16(pa.h, vb.h, oacc, 0, 0, 0);
            }
        }
    }

    float l = (lacc.x + lacc.y) + (lacc.z + lacc.w);
    l += __shfl_xor(l, 16);
    l += __shfl_xor(l, 32);

    float* Ob = O + ((size_t)bh*HW + q0 + w*16) * DH;
    #pragma unroll
    for (int r = 0; r < 4; ++r) {
        float lr = __shfl(l, 4*g + r);
        float ov = (r==0? oacc.x : r==1? oacc.y : r==2? oacc.z : oacc.w);
        Ob[(4*g + r)*DH + qc] = ov / lr;
    }
}

// ---------------------------------------------------------------------------
// Kernel C: proj 1x1 conv + transpose. 1024 blocks x 256 thr, 8 pixels each.
// ---------------------------------------------------------------------------
__global__ __launch_bounds__(256) void proj_kernel(
    const float* __restrict__ O, const float* __restrict__ proj_w,
    const float* __restrict__ proj_b, float* __restrict__ y)
{
    const int PIX = 8;
    __shared__ float os[PIX][NC];
    __shared__ float ys[NC][PIX+1];
    int blk = blockIdx.x;                // 1024
    int b   = blk >> 9;
    int p0  = (blk & 511) * PIX;
    int tid = threadIdx.x;
    int c   = tid & 63;
    int pg  = tid >> 6;                  // 0..3 -> pixels pg*2, pg*2+1

    for (int idx = tid; idx < PIX*NC; idx += 256) {
        int pp = idx >> 6;
        int cp = idx & 63;
        os[pp][cp] = O[((size_t)(b*NHD + (cp>>4)))*HW*DH + (size_t)(p0+pp)*DH + (cp & 15)];
    }
    float wv[NC];
    #pragma unroll
    for (int c4 = 0; c4 < NC/4; c4++) {
        float4 t = ((const float4*)(proj_w + c*NC))[c4];
        wv[4*c4+0] = t.x; wv[4*c4+1] = t.y; wv[4*c4+2] = t.z; wv[4*c4+3] = t.w;
    }
    float bias = proj_b[c];
    __syncthreads();

    #pragma unroll
    for (int u = 0; u < 2; ++u) {
        int pi = pg*2 + u;
        float a0 = 0.f, a1 = 0.f, a2 = 0.f, a3 = 0.f;
        #pragma unroll
        for (int c4 = 0; c4 < NC/4; c4++) {
            float4 ov = ((const float4*)os[pi])[c4];
            a0 = fmaf(wv[4*c4+0], ov.x, a0);
            a1 = fmaf(wv[4*c4+1], ov.y, a1);
            a2 = fmaf(wv[4*c4+2], ov.z, a2);
            a3 = fmaf(wv[4*c4+3], ov.w, a3);
        }
        ys[c][pi] = bias + ((a0 + a1) + (a2 + a3));
    }
    __syncthreads();
    for (int idx = tid; idx < PIX*NC; idx += 256) {
        int cc = idx >> 3;
        int i  = idx & 7;
        y[(size_t)(b*NC + cc)*HW + p0 + i] = ys[cc][i];
    }
}

// ---------------------------------------------------------------------------
extern "C" void kernel_launch(void* const* d_in, const int* in_sizes, int n_in,
                              void* d_out, int out_size, void* d_ws, size_t ws_size,
                              hipStream_t stream)
{
    const float* x      = (const float*)d_in[0];
    const float* illu   = (const float*)d_in[1];
    const float* qkv_w  = (const float*)d_in[2];
    const float* qkv_b  = (const float*)d_in[3];
    const float* illu_w = (const float*)d_in[4];
    const float* illu_b = (const float*)d_in[5];
    const float* proj_w = (const float*)d_in[6];
    const float* proj_b = (const float*)d_in[7];
    float* out = (float*)d_out;

    ushort* Qx = (ushort*)d_ws;                     // 2MB (hi|lo)
    ushort* Kx = Qx + (size_t)NBH*HW*32;            // 2MB (hi|lo)
    ushort* Vt = Kx + (size_t)NBH*HW*32;            // 1MB [bh][d][key]
    float*  O  = (float*)(Vt + (size_t)NBH*HW*DH);  // 2MB fp32

    hipLaunchKernelGGL(qkv_kernel, dim3(1024), dim3(192), 0, stream,
                       x, illu, qkv_w, qkv_b, illu_w, illu_b, Qx, Kx, Vt);
    hipLaunchKernelGGL(attn_kernel, dim3(1024), dim3(128), 0, stream,
                       Qx, Kx, Vt, O);
    hipLaunchKernelGGL(proj_kernel, dim3(1024), dim3(256), 0, stream,
                       O, proj_w, proj_b, out);
}

// Round 6
// 73.271 us; speedup vs baseline: 1.6593x; 1.6593x over previous
//
#include <hip/hip_runtime.h>
#include <hip/hip_bf16.h>
#include <math.h>

#define HW   4096
#define NC   64
#define NB   2
#define NHD  4
#define DH   16
#define NBH  (NB*NHD)

typedef __attribute__((ext_vector_type(4))) float f32x4;
typedef __attribute__((ext_vector_type(8))) short bf16x8;
typedef __attribute__((ext_vector_type(2))) unsigned int uint2v;

#define QSCALE 0.36067376022224087f   // 0.25 * log2(e)

static __device__ __forceinline__ unsigned short bf16_bits(float f) {
    union { __hip_bfloat16 h; unsigned short u; } cv;
    cv.h = __float2bfloat16(f);
    return cv.u;
}
static __device__ __forceinline__ float bits_to_f(unsigned short b) {
    return __uint_as_float(((unsigned int)b) << 16);
}
static __device__ __forceinline__ unsigned int cvt_pk_bf16(float lo, float hi) {
    unsigned int r;
    asm("v_cvt_pk_bf16_f32 %0, %1, %2" : "=v"(r) : "v"(lo), "v"(hi));
    return r;
}

// ---------------------------------------------------------------------------
// Kernel A: qkv + illu 1x1 convs. 512 blocks x 192 thr, 16 pixels/block.
// Q (pre-scaled 0.25*log2e) and K (=k+illu) DOUBLE-BF16 [bh][p][32]
// (d0-15 hi, d16-31 lo). V single bf16 transposed Vt [bh][d][key].
// Outputs staged in LDS, written coalesced (16B/lane contiguous chunks).
// ---------------------------------------------------------------------------
__global__ __launch_bounds__(192) void qkv_kernel(
    const float* __restrict__ x, const float* __restrict__ illu,
    const float* __restrict__ qkv_w, const float* __restrict__ qkv_b,
    const float* __restrict__ illu_w, const float* __restrict__ illu_b,
    ushort* __restrict__ Qx, ushort* __restrict__ Kx, ushort* __restrict__ Vt)
{
    const int PIX = 16;
    __shared__ float  xs[PIX][NC];          // 4KB
    __shared__ float  fs[PIX][NC];          // 4KB
    __shared__ ushort qs[NHD][PIX][32];     // 4KB  [head][p][hi0-15|lo16-31]
    __shared__ ushort ks[NHD][PIX][32];     // 4KB
    __shared__ ushort vs[NC][PIX];          // 2KB  [co][p]
    int blk = blockIdx.x;                   // 512
    int b   = blk >> 8;
    int p0  = (blk & 255) * PIX;
    int tid = threadIdx.x;

    for (int idx = tid; idx < PIX*NC; idx += 192) {
        int ch = idx >> 4;
        int pp = idx & 15;
        xs[pp][ch] = x   [(b*NC + ch)*HW + p0 + pp];
        fs[pp][ch] = illu[(b*NC + ch)*HW + p0 + pp];
    }

    int role = tid / 64;                    // 0=q 1=k 2=v
    int co   = tid & 63;                    // head*16 + dd
    int head = co >> 4;
    int dd   = co & 15;

    float wq[NC];
    #pragma unroll
    for (int c4 = 0; c4 < NC/4; c4++) {
        float4 w = ((const float4*)(qkv_w + tid*NC))[c4];
        wq[4*c4+0] = w.x; wq[4*c4+1] = w.y; wq[4*c4+2] = w.z; wq[4*c4+3] = w.w;
    }
    float bias = qkv_b[tid];
    float wi[NC];
    if (role == 1) {
        #pragma unroll
        for (int c4 = 0; c4 < NC/4; c4++) {
            float4 w = ((const float4*)(illu_w + co*NC))[c4];
            wi[4*c4+0] = w.x; wi[4*c4+1] = w.y; wi[4*c4+2] = w.z; wi[4*c4+3] = w.w;
        }
        bias += illu_b[co];
    }
    __syncthreads();

    #pragma unroll
    for (int pp = 0; pp < PIX; pp++) {
        float a0 = 0.f, a1 = 0.f, a2 = 0.f, a3 = 0.f;
        #pragma unroll
        for (int c4 = 0; c4 < NC/4; c4++) {
            float4 xv = ((const float4*)xs[pp])[c4];
            a0 = fmaf(wq[4*c4+0], xv.x, a0);
            a1 = fmaf(wq[4*c4+1], xv.y, a1);
            a2 = fmaf(wq[4*c4+2], xv.z, a2);
            a3 = fmaf(wq[4*c4+3], xv.w, a3);
        }
        float acc = bias + ((a0 + a1) + (a2 + a3));
        if (role == 1) {
            float b0 = 0.f, b1 = 0.f, b2 = 0.f, b3 = 0.f;
            #pragma unroll
            for (int c4 = 0; c4 < NC/4; c4++) {
                float4 iv = ((const float4*)fs[pp])[c4];
                b0 = fmaf(wi[4*c4+0], iv.x, b0);
                b1 = fmaf(wi[4*c4+1], iv.y, b1);
                b2 = fmaf(wi[4*c4+2], iv.z, b2);
                b3 = fmaf(wi[4*c4+3], iv.w, b3);
            }
            acc += ((b0 + b1) + (b2 + b3));
        }
        if (role == 0) {
            float v = acc * QSCALE;
            unsigned short hb = bf16_bits(v);
            qs[head][pp][dd]      = hb;
            qs[head][pp][16 + dd] = bf16_bits(v - bits_to_f(hb));
        } else if (role == 1) {
            unsigned short hb = bf16_bits(acc);
            ks[head][pp][dd]      = hb;
            ks[head][pp][16 + dd] = bf16_bits(acc - bits_to_f(hb));
        } else {
            vs[co][pp] = bf16_bits(acc);
        }
    }
    __syncthreads();

    // cooperative coalesced writes: Q 256 + K 256 + V 128 = 640 x 16B
    const ushort* qf = &qs[0][0][0];
    const ushort* kf = &ks[0][0][0];
    const ushort* vf = &vs[0][0];
    for (int u = tid; u < 640; u += 192) {
        if (u < 256) {
            int h = u >> 6, inner = u & 63;       // 64 x 16B per head
            *(bf16x8*)(Qx + ((size_t)(b*NHD + h))*HW*32 + (size_t)p0*32 + inner*8)
                = *(const bf16x8*)(qf + h*PIX*32 + inner*8);
        } else if (u < 512) {
            int h = (u - 256) >> 6, inner = (u - 256) & 63;
            *(bf16x8*)(Kx + ((size_t)(b*NHD + h))*HW*32 + (size_t)p0*32 + inner*8)
                = *(const bf16x8*)(kf + h*PIX*32 + inner*8);
        } else {
            int t2 = u - 512;                     // 128: co = t2>>1, half = t2&1
            int cc = t2 >> 1, half = t2 & 1;
            *(bf16x8*)(Vt + ((size_t)(b*NC + cc))*HW + p0 + half*8)
                = *(const bf16x8*)(vf + cc*PIX + half*8);
        }
    }
}

// ---------------------------------------------------------------------------
// Kernel B: MFMA flash attention. 512 blocks x 256 thr (4 waves x 16 q-rows).
// Double-buffered LDS, ONE barrier per tile, global->reg prefetch of tile
// t+1 overlapped with compute of tile t (async-STAGE split).
// Swapped QK^T: mfma(K,Q), K double-bf16 (hi|lo in K=32 slots),
// B1=[Qhi|Qhi], B2=[Qlo|Qlo]. P single bf16 via v_cvt_pk. No-max softmax.
// ---------------------------------------------------------------------------
#define KT 128
#define NT (HW/KT)   // 32 tiles

__global__ __launch_bounds__(256) void attn_kernel(
    const ushort* __restrict__ Qx, const ushort* __restrict__ Kx,
    const ushort* __restrict__ Vt, float* __restrict__ O)
{
    __shared__ alignas(16) ushort Ks[2][128*32];   // 16KB  XOR-swizzled slots
    __shared__ alignas(16) ushort Vs[2][16*136];   // 8.5KB [d][136 pad]

    int blk  = blockIdx.x;               // 512
    int bh   = blk >> 6;
    int q0   = (blk & 63) * 64;
    int tid  = threadIdx.x;              // 0..255
    int w    = tid >> 6;                 // wave 0..3
    int lane = tid & 63;
    int g    = lane >> 4;                // lane group 0..3
    int qc   = lane & 15;                // query col / A-row / V d-col

    const ushort* Qb = Qx + (size_t)bh*HW*32;
    const ushort* Kb = Kx + (size_t)bh*HW*32;
    const ushort* Vb = Vt + (size_t)bh*DH*HW;

    int qrow = q0 + w*16 + qc;
    bf16x8 qhi = *(const bf16x8*)(Qb + (size_t)qrow*32 +      8*(g&1));
    bf16x8 qlo = *(const bf16x8*)(Qb + (size_t)qrow*32 + 16 + 8*(g&1));

    f32x4 zero4 = {0.f, 0.f, 0.f, 0.f};
    f32x4 oacc  = {0.f, 0.f, 0.f, 0.f};
    f32x4 lacc  = {0.f, 0.f, 0.f, 0.f};

    // compute-side lane-constant addressing
    int mconst = (qc & 3) ^ ((qc >> 2) & 3);
    const int koff = qc*32 + ((g ^ mconst)*8);
    const int voff = qc*136 + 4*g;

    // staging-side thread-constant addressing (2 K chunks + 1 V chunk)
    int f0 = tid,        r0 = f0 >> 2, h0 = f0 & 3;
    int f1 = tid + 256,  r1 = f1 >> 2, h1 = f1 & 3;
    int s0 = (h0 ^ ((r0 & 3) ^ ((r0 >> 2) & 3))) * 8;
    int s1 = (h1 ^ ((r1 & 3) ^ ((r1 >> 2) & 3))) * 8;
    int vd = tid >> 4, vseg = tid & 15;

    // prologue: tile 0 -> regs -> buf0
    bf16x8 gk0 = *(const bf16x8*)(Kb + (size_t)r0*32 + 8*h0);
    bf16x8 gk1 = *(const bf16x8*)(Kb + (size_t)r1*32 + 8*h1);
    bf16x8 gv  = *(const bf16x8*)(Vb + (size_t)vd*HW + vseg*8);
    *(bf16x8*)(&Ks[0][0] + r0*32 + s0) = gk0;
    *(bf16x8*)(&Ks[0][0] + r1*32 + s1) = gk1;
    *(bf16x8*)(&Vs[0][0] + vd*136 + vseg*8) = gv;

    for (int t = 0; t < NT; ++t) {
        __syncthreads();                 // buf[t&1] ready; buf[(t+1)&1] free
        if (t + 1 < NT) {                // prefetch tile t+1 into regs
            int kt = (t + 1) * KT;
            gk0 = *(const bf16x8*)(Kb + (size_t)(kt + r0)*32 + 8*h0);
            gk1 = *(const bf16x8*)(Kb + (size_t)(kt + r1)*32 + 8*h1);
            gv  = *(const bf16x8*)(Vb + (size_t)vd*HW + kt + vseg*8);
        }

        const ushort* kr = &Ks[t & 1][0] + koff;
        const ushort* vr = &Vs[t & 1][0] + voff;
        unsigned int pe0 = 0, pe1 = 0;
        #pragma unroll
        for (int kb = 0; kb < 8; ++kb) {
            bf16x8 kfrag = *(const bf16x8*)(kr + kb*512);
            f32x4 s = __builtin_amdgcn_mfma_f32_16x16x32_bf16(kfrag, qhi, zero4, 0, 0, 0);
            s = __builtin_amdgcn_mfma_f32_16x16x32_bf16(kfrag, qlo, s, 0, 0, 0);
            float p0 = __builtin_amdgcn_exp2f(s.x);
            float p1 = __builtin_amdgcn_exp2f(s.y);
            float p2 = __builtin_amdgcn_exp2f(s.z);
            float p3 = __builtin_amdgcn_exp2f(s.w);
            lacc.x += p0; lacc.y += p1; lacc.z += p2; lacc.w += p3;
            unsigned int plo = cvt_pk_bf16(p0, p1);
            unsigned int phi = cvt_pk_bf16(p2, p3);
            if ((kb & 1) == 0) { pe0 = plo; pe1 = phi; }
            else {
                uint2v vE = *(const uint2v*)(vr + (kb-1)*16);
                uint2v vO = *(const uint2v*)(vr + kb*16);
                union { unsigned int u[4]; bf16x8 h; } pa, vb;
                pa.u[0] = pe0;  pa.u[1] = pe1;  pa.u[2] = plo;  pa.u[3] = phi;
                vb.u[0] = vE.x; vb.u[1] = vE.y; vb.u[2] = vO.x; vb.u[3] = vO.y;
                oacc = __builtin_amdgcn_mfma_f32_16x16x32_bf16(pa.h, vb.h, oacc, 0, 0, 0);
            }
        }

        if (t + 1 < NT) {                // write prefetched regs -> other buf
            int nb = (t + 1) & 1;
            *(bf16x8*)(&Ks[nb][0] + r0*32 + s0) = gk0;
            *(bf16x8*)(&Ks[nb][0] + r1*32 + s1) = gk1;
            *(bf16x8*)(&Vs[nb][0] + vd*136 + vseg*8) = gv;
        }
    }

    float l = (lacc.x + lacc.y) + (lacc.z + lacc.w);
    l += __shfl_xor(l, 16);
    l += __shfl_xor(l, 32);

    float* Ob = O + ((size_t)bh*HW + q0 + w*16) * DH;
    #pragma unroll
    for (int r = 0; r < 4; ++r) {
        float lr = __shfl(l, 4*g + r);
        float ov = (r==0? oacc.x : r==1? oacc.y : r==2? oacc.z : oacc.w);
        Ob[(4*g + r)*DH + qc] = ov / lr;
    }
}

// ---------------------------------------------------------------------------
// Kernel C: proj 1x1 conv + transpose. 512 blocks x 256 thr, 16 pixels each.
// ---------------------------------------------------------------------------
__global__ __launch_bounds__(256) void proj_kernel(
    const float* __restrict__ O, const float* __restrict__ proj_w,
    const float* __restrict__ proj_b, float* __restrict__ y)
{
    const int PIX = 16;
    __shared__ float os[PIX][NC];        // 4KB
    __shared__ float ys[NC][PIX+1];      // padded
    int blk = blockIdx.x;                // 512
    int b   = blk >> 8;
    int p0  = (blk & 255) * PIX;
    int tid = threadIdx.x;
    int c   = tid & 63;
    int pg  = tid >> 6;                  // 0..3 -> pixels pg*4+u

    for (int idx = tid; idx < PIX*NC; idx += 256) {
        int pp = idx >> 6;
        int cp = idx & 63;
        os[pp][cp] = O[((size_t)(b*NHD + (cp>>4)))*HW*DH + (size_t)(p0+pp)*DH + (cp & 15)];
    }
    float wv[NC];
    #pragma unroll
    for (int c4 = 0; c4 < NC/4; c4++) {
        float4 t = ((const float4*)(proj_w + c*NC))[c4];
        wv[4*c4+0] = t.x; wv[4*c4+1] = t.y; wv[4*c4+2] = t.z; wv[4*c4+3] = t.w;
    }
    float bias = proj_b[c];
    __syncthreads();

    #pragma unroll
    for (int u = 0; u < 4; ++u) {
        int pi = pg*4 + u;
        float a0 = 0.f, a1 = 0.f, a2 = 0.f, a3 = 0.f;
        #pragma unroll
        for (int c4 = 0; c4 < NC/4; c4++) {
            float4 ov = ((const float4*)os[pi])[c4];
            a0 = fmaf(wv[4*c4+0], ov.x, a0);
            a1 = fmaf(wv[4*c4+1], ov.y, a1);
            a2 = fmaf(wv[4*c4+2], ov.z, a2);
            a3 = fmaf(wv[4*c4+3], ov.w, a3);
        }
        ys[c][pi] = bias + ((a0 + a1) + (a2 + a3));
    }
    __syncthreads();
    for (int idx = tid; idx < PIX*NC; idx += 256) {
        int cc = idx >> 4;
        int i  = idx & 15;
        y[(size_t)(b*NC + cc)*HW + p0 + i] = ys[cc][i];
    }
}

// ---------------------------------------------------------------------------
extern "C" void kernel_launch(void* const* d_in, const int* in_sizes, int n_in,
                              void* d_out, int out_size, void* d_ws, size_t ws_size,
                              hipStream_t stream)
{
    const float* x      = (const float*)d_in[0];
    const float* illu   = (const float*)d_in[1];
    const float* qkv_w  = (const float*)d_in[2];
    const float* qkv_b  = (const float*)d_in[3];
    const float* illu_w = (const float*)d_in[4];
    const float* illu_b = (const float*)d_in[5];
    const float* proj_w = (const float*)d_in[6];
    const float* proj_b = (const float*)d_in[7];
    float* out = (float*)d_out;

    ushort* Qx = (ushort*)d_ws;                     // 2MB (hi|lo)
    ushort* Kx = Qx + (size_t)NBH*HW*32;            // 2MB (hi|lo)
    ushort* Vt = Kx + (size_t)NBH*HW*32;            // 1MB [bh][d][key]
    float*  O  = (float*)(Vt + (size_t)NBH*HW*DH);  // 2MB fp32

    hipLaunchKernelGGL(qkv_kernel, dim3(512), dim3(192), 0, stream,
                       x, illu, qkv_w, qkv_b, illu_w, illu_b, Qx, Kx, Vt);
    hipLaunchKernelGGL(attn_kernel, dim3(512), dim3(256), 0, stream,
                       Qx, Kx, Vt, O);
    hipLaunchKernelGGL(proj_kernel, dim3(512), dim3(256), 0, stream,
                       O, proj_w, proj_b, out);
}

// Round 7
// 61.547 us; speedup vs baseline: 1.9754x; 1.1905x over previous
//
#include <hip/hip_runtime.h>
#include <hip/hip_bf16.h>
#include <math.h>

#define HW   4096
#define NC   64
#define NB   2
#define NHD  4
#define DH   16
#define NBH  (NB*NHD)

typedef __attribute__((ext_vector_type(4))) float f32x4;
typedef __attribute__((ext_vector_type(8))) short bf16x8;
typedef __attribute__((ext_vector_type(2))) unsigned int uint2v;

#define QSCALE 0.36067376022224087f   // 0.25 * log2(e)

static __device__ __forceinline__ unsigned short bf16_bits(float f) {
    union { __hip_bfloat16 h; unsigned short u; } cv;
    cv.h = __float2bfloat16(f);
    return cv.u;
}
static __device__ __forceinline__ float bits_to_f(unsigned short b) {
    return __uint_as_float(((unsigned int)b) << 16);
}
static __device__ __forceinline__ unsigned int cvt_pk_bf16(float lo, float hi) {
    unsigned int r;
    asm("v_cvt_pk_bf16_f32 %0, %1, %2" : "=v"(r) : "v"(lo), "v"(hi));
    return r;
}

// ---------------------------------------------------------------------------
// Kernel A: qkv + illu 1x1 convs. 1024 blocks x 256 thr (4 balanced waves:
// q / k_qkv / illu / v), 8 pixels/block. K = k_qkv + k_illu summed via LDS.
// Q (pre-scaled 0.25*log2e) and K DOUBLE-BF16 [bh][p][32] (hi 0-15, lo 16-31).
// V single bf16 transposed Vt [bh][d][key]. Coalesced 16B-chunk writes.
// ---------------------------------------------------------------------------
__global__ __launch_bounds__(256) void qkv_kernel(
    const float* __restrict__ x, const float* __restrict__ illu,
    const float* __restrict__ qkv_w, const float* __restrict__ qkv_b,
    const float* __restrict__ illu_w, const float* __restrict__ illu_b,
    ushort* __restrict__ Qx, ushort* __restrict__ Kx, ushort* __restrict__ Vt)
{
    const int PIX = 8;
    __shared__ float  xs[PIX][NC];          // 2KB
    __shared__ float  fs[PIX][NC];          // 2KB
    __shared__ float  kp1[PIX][NC];         // 2KB  k_qkv partial
    __shared__ float  kp2[PIX][NC];         // 2KB  k_illu partial
    __shared__ ushort qs[NHD][PIX][32];     // 2KB
    __shared__ ushort ks[NHD][PIX][32];     // 2KB
    __shared__ ushort vs[NC][PIX];          // 1KB
    int blk = blockIdx.x;                   // 1024
    int b   = blk >> 9;
    int p0  = (blk & 511) * PIX;
    int tid = threadIdx.x;

    for (int idx = tid; idx < PIX*NC; idx += 256) {
        int ch = idx >> 3;
        int pp = idx & 7;
        xs[pp][ch] = x   [(b*NC + ch)*HW + p0 + pp];
        fs[pp][ch] = illu[(b*NC + ch)*HW + p0 + pp];
    }

    int role = tid >> 6;                    // 0=q 1=k_qkv 2=illu 3=v
    int co   = tid & 63;                    // head*16 + dd
    int head = co >> 4;
    int dd   = co & 15;

    const float* wrow = (role == 0) ? qkv_w  + (size_t)co*NC
                      : (role == 1) ? qkv_w  + (size_t)(64 + co)*NC
                      : (role == 2) ? illu_w + (size_t)co*NC
                      :               qkv_w  + (size_t)(128 + co)*NC;
    float bias = (role == 0) ? qkv_b[co]
               : (role == 1) ? qkv_b[64 + co]
               : (role == 2) ? illu_b[co]
               :               qkv_b[128 + co];

    float wq[NC];
    #pragma unroll
    for (int c4 = 0; c4 < NC/4; c4++) {
        float4 w = ((const float4*)wrow)[c4];
        wq[4*c4+0] = w.x; wq[4*c4+1] = w.y; wq[4*c4+2] = w.z; wq[4*c4+3] = w.w;
    }
    __syncthreads();

    const float* srcBase = (role == 2) ? &fs[0][0] : &xs[0][0];
    #pragma unroll
    for (int pp = 0; pp < PIX; pp++) {
        float a0 = 0.f, a1 = 0.f, a2 = 0.f, a3 = 0.f;
        const float4* sp = (const float4*)(srcBase + pp*NC);
        #pragma unroll
        for (int c4 = 0; c4 < NC/4; c4++) {
            float4 xv = sp[c4];
            a0 = fmaf(wq[4*c4+0], xv.x, a0);
            a1 = fmaf(wq[4*c4+1], xv.y, a1);
            a2 = fmaf(wq[4*c4+2], xv.z, a2);
            a3 = fmaf(wq[4*c4+3], xv.w, a3);
        }
        float acc = bias + ((a0 + a1) + (a2 + a3));
        if (role == 0) {
            float v = acc * QSCALE;
            unsigned short hb = bf16_bits(v);
            qs[head][pp][dd]      = hb;
            qs[head][pp][16 + dd] = bf16_bits(v - bits_to_f(hb));
        } else if (role == 1) {
            kp1[pp][co] = acc;
        } else if (role == 2) {
            kp2[pp][co] = acc;
        } else {
            vs[co][pp] = bf16_bits(acc);
        }
    }
    __syncthreads();
    if (role == 1) {                        // finalize K = k_qkv + k_illu
        #pragma unroll
        for (int pp = 0; pp < PIX; pp++) {
            float a = kp1[pp][co] + kp2[pp][co];
            unsigned short hb = bf16_bits(a);
            ks[head][pp][dd]      = hb;
            ks[head][pp][16 + dd] = bf16_bits(a - bits_to_f(hb));
        }
    }
    __syncthreads();

    // cooperative coalesced writes: Q 128 + K 128 + V 64 = 320 x 16B chunks
    const ushort* qf = &qs[0][0][0];
    const ushort* kf = &ks[0][0][0];
    for (int u = tid; u < 320; u += 256) {
        if (u < 128) {
            int h = u >> 5, inner = u & 31;        // 32 chunks per head
            *(bf16x8*)(Qx + ((size_t)(b*NHD + h))*HW*32 + (size_t)p0*32 + inner*8)
                = *(const bf16x8*)(qf + h*PIX*32 + inner*8);
        } else if (u < 256) {
            int h = (u - 128) >> 5, inner = (u - 128) & 31;
            *(bf16x8*)(Kx + ((size_t)(b*NHD + h))*HW*32 + (size_t)p0*32 + inner*8)
                = *(const bf16x8*)(kf + h*PIX*32 + inner*8);
        } else {
            int cc = u - 256;                      // 64 chunks: one per channel
            *(bf16x8*)(Vt + ((size_t)(b*NC + cc))*HW + p0)
                = *(const bf16x8*)(&vs[cc][0]);
        }
    }
}

// ---------------------------------------------------------------------------
// Kernel B: MFMA flash attention with in-block split-K.
// 512 blocks x 512 thr = 8 waves: wave w -> split s=w>>2 (keys s*2048..),
// q-group qg=w&3 (rows q0+qg*16..). Each split double-buffers its own
// K/V LDS tiles; ONE barrier per tile; global->reg prefetch overlaps compute.
// Swapped QK^T: mfma(K,Q), K double-bf16 (hi|lo in K=32 slots),
// B1=[Qhi|Qhi], B2=[Qlo|Qlo]. P single bf16 via v_cvt_pk. No-max softmax.
// Split partials (oacc,l) merged via LDS. O written as [b][p][64].
// ---------------------------------------------------------------------------
#define KT   128
#define KPS  2048          // keys per split
#define NTS  (KPS/KT)      // 16 tiles per split

__global__ __launch_bounds__(512) void attn_kernel(
    const ushort* __restrict__ Qx, const ushort* __restrict__ Kx,
    const ushort* __restrict__ Vt, float* __restrict__ O)
{
    __shared__ alignas(16) ushort Ks[2][2][128*32];  // 32KB  [split][buf]
    __shared__ alignas(16) ushort Vs[2][2][16*136];  // 17KB
    __shared__ float mrg[4][64][5];                  // 5KB   split-1 partials

    int blk  = blockIdx.x;               // 512
    int bh   = blk >> 6;
    int q0   = (blk & 63) * 64;
    int tid  = threadIdx.x;              // 0..511
    int w    = tid >> 6;                 // wave 0..7
    int s    = w >> 2;                   // key split 0..1
    int qg   = w & 3;                    // q-group 0..3
    int lane = tid & 63;
    int g    = lane >> 4;                // lane group 0..3
    int qc   = lane & 15;                // query col / A-row / V d-col

    const ushort* Qb = Qx + (size_t)bh*HW*32;
    const ushort* Kb = Kx + (size_t)bh*HW*32 + (size_t)s*KPS*32;
    const ushort* Vb = Vt + (size_t)bh*DH*HW;  // key offset added per access

    int qrow = q0 + qg*16 + qc;
    bf16x8 qhi = *(const bf16x8*)(Qb + (size_t)qrow*32 +      8*(g&1));
    bf16x8 qlo = *(const bf16x8*)(Qb + (size_t)qrow*32 + 16 + 8*(g&1));

    f32x4 zero4 = {0.f, 0.f, 0.f, 0.f};
    f32x4 oacc  = {0.f, 0.f, 0.f, 0.f};
    f32x4 lacc  = {0.f, 0.f, 0.f, 0.f};

    // compute-side lane-constant addressing
    int mconst = (qc & 3) ^ ((qc >> 2) & 3);
    const int koff = qc*32 + ((g ^ mconst)*8);
    const int voff = qc*136 + 4*g;

    // staging-side thread-constant addressing (group = 256 thr of this split)
    int gt = tid & 255;
    int f0 = gt,        r0 = f0 >> 2, h0 = f0 & 3;
    int f1 = gt + 256,  r1 = f1 >> 2, h1 = f1 & 3;
    int s0 = (h0 ^ ((r0 & 3) ^ ((r0 >> 2) & 3))) * 8;
    int s1 = (h1 ^ ((r1 & 3) ^ ((r1 >> 2) & 3))) * 8;
    int vd = gt >> 4, vseg = gt & 15;

    // prologue: tile 0 of this split -> regs -> buf0
    bf16x8 gk0 = *(const bf16x8*)(Kb + (size_t)r0*32 + 8*h0);
    bf16x8 gk1 = *(const bf16x8*)(Kb + (size_t)r1*32 + 8*h1);
    bf16x8 gv  = *(const bf16x8*)(Vb + (size_t)vd*HW + s*KPS + vseg*8);
    *(bf16x8*)(&Ks[s][0][0] + r0*32 + s0) = gk0;
    *(bf16x8*)(&Ks[s][0][0] + r1*32 + s1) = gk1;
    *(bf16x8*)(&Vs[s][0][0] + vd*136 + vseg*8) = gv;

    for (int t = 0; t < NTS; ++t) {
        __syncthreads();
        if (t + 1 < NTS) {               // prefetch tile t+1 into regs
            int kt = (t + 1) * KT;
            gk0 = *(const bf16x8*)(Kb + (size_t)(kt + r0)*32 + 8*h0);
            gk1 = *(const bf16x8*)(Kb + (size_t)(kt + r1)*32 + 8*h1);
            gv  = *(const bf16x8*)(Vb + (size_t)vd*HW + s*KPS + kt + vseg*8);
        }

        const ushort* kr = &Ks[s][t & 1][0] + koff;
        const ushort* vr = &Vs[s][t & 1][0] + voff;
        unsigned int pe0 = 0, pe1 = 0;
        #pragma unroll
        for (int kb = 0; kb < 8; ++kb) {
            bf16x8 kfrag = *(const bf16x8*)(kr + kb*512);
            f32x4 sS = __builtin_amdgcn_mfma_f32_16x16x32_bf16(kfrag, qhi, zero4, 0, 0, 0);
            sS = __builtin_amdgcn_mfma_f32_16x16x32_bf16(kfrag, qlo, sS, 0, 0, 0);
            float p0 = __builtin_amdgcn_exp2f(sS.x);
            float p1 = __builtin_amdgcn_exp2f(sS.y);
            float p2 = __builtin_amdgcn_exp2f(sS.z);
            float p3 = __builtin_amdgcn_exp2f(sS.w);
            lacc.x += p0; lacc.y += p1; lacc.z += p2; lacc.w += p3;
            unsigned int plo = cvt_pk_bf16(p0, p1);
            unsigned int phi = cvt_pk_bf16(p2, p3);
            if ((kb & 1) == 0) { pe0 = plo; pe1 = phi; }
            else {
                uint2v vE = *(const uint2v*)(vr + (kb-1)*16);
                uint2v vO = *(const uint2v*)(vr + kb*16);
                union { unsigned int u[4]; bf16x8 h; } pa, vb;
                pa.u[0] = pe0;  pa.u[1] = pe1;  pa.u[2] = plo;  pa.u[3] = phi;
                vb.u[0] = vE.x; vb.u[1] = vE.y; vb.u[2] = vO.x; vb.u[3] = vO.y;
                oacc = __builtin_amdgcn_mfma_f32_16x16x32_bf16(pa.h, vb.h, oacc, 0, 0, 0);
            }
        }

        if (t + 1 < NTS) {               // write prefetched regs -> other buf
            int nb = (t + 1) & 1;
            *(bf16x8*)(&Ks[s][nb][0] + r0*32 + s0) = gk0;
            *(bf16x8*)(&Ks[s][nb][0] + r1*32 + s1) = gk1;
            *(bf16x8*)(&Vs[s][nb][0] + vd*136 + vseg*8) = gv;
        }
    }

    // split-local denominator reduce (all lanes of qc hold same l after this)
    float l = (lacc.x + lacc.y) + (lacc.z + lacc.w);
    l += __shfl_xor(l, 16);
    l += __shfl_xor(l, 32);

    // merge split 1 -> split 0 via LDS
    __syncthreads();
    if (s == 1) {
        float* m = &mrg[qg][lane][0];
        m[0] = oacc.x; m[1] = oacc.y; m[2] = oacc.z; m[3] = oacc.w; m[4] = l;
    }
    __syncthreads();
    if (s == 0) {
        const float* m = &mrg[qg][lane][0];
        oacc.x += m[0]; oacc.y += m[1]; oacc.z += m[2]; oacc.w += m[3];
        l += m[4];
        int b = bh >> 2, h = bh & 3;
        float* Ob = O + ((size_t)b*HW + q0 + qg*16)*NC + h*DH;
        #pragma unroll
        for (int r = 0; r < 4; ++r) {
            float lr = __shfl(l, 4*g + r);
            float ov = (r==0? oacc.x : r==1? oacc.y : r==2? oacc.z : oacc.w);
            Ob[(4*g + r)*NC + qc] = ov / lr;
        }
    }
}

// ---------------------------------------------------------------------------
// Kernel C: proj 1x1 conv + transpose. 1024 blocks x 256 thr, 8 pixels each.
// O is [b][p][64] -> fully contiguous input loads.
// ---------------------------------------------------------------------------
__global__ __launch_bounds__(256) void proj_kernel(
    const float* __restrict__ O, const float* __restrict__ proj_w,
    const float* __restrict__ proj_b, float* __restrict__ y)
{
    const int PIX = 8;
    __shared__ float os[PIX][NC];        // 2KB
    __shared__ float ys[NC][PIX+1];
    int blk = blockIdx.x;                // 1024
    int b   = blk >> 9;
    int p0  = (blk & 511) * PIX;
    int tid = threadIdx.x;
    int c   = tid & 63;
    int pg  = tid >> 6;                  // 0..3 -> pixels pg*2+u

    if (tid < PIX*NC/4) {                // 128 float4 contiguous loads
        int pp = tid >> 4, c4 = tid & 15;
        ((float4*)os[pp])[c4] = ((const float4*)(O + ((size_t)(b*HW + p0 + pp))*NC))[c4];
    }
    float wv[NC];
    #pragma unroll
    for (int c4 = 0; c4 < NC/4; c4++) {
        float4 t = ((const float4*)(proj_w + (size_t)c*NC))[c4];
        wv[4*c4+0] = t.x; wv[4*c4+1] = t.y; wv[4*c4+2] = t.z; wv[4*c4+3] = t.w;
    }
    float bias = proj_b[c];
    __syncthreads();

    #pragma unroll
    for (int u = 0; u < 2; ++u) {
        int pi = pg*2 + u;
        float a0 = 0.f, a1 = 0.f, a2 = 0.f, a3 = 0.f;
        #pragma unroll
        for (int c4 = 0; c4 < NC/4; c4++) {
            float4 ov = ((const float4*)os[pi])[c4];
            a0 = fmaf(wv[4*c4+0], ov.x, a0);
            a1 = fmaf(wv[4*c4+1], ov.y, a1);
            a2 = fmaf(wv[4*c4+2], ov.z, a2);
            a3 = fmaf(wv[4*c4+3], ov.w, a3);
        }
        ys[c][pi] = bias + ((a0 + a1) + (a2 + a3));
    }
    __syncthreads();
    for (int idx = tid; idx < PIX*NC; idx += 256) {
        int cc = idx >> 3;
        int i  = idx & 7;
        y[(size_t)(b*NC + cc)*HW + p0 + i] = ys[cc][i];
    }
}

// ---------------------------------------------------------------------------
extern "C" void kernel_launch(void* const* d_in, const int* in_sizes, int n_in,
                              void* d_out, int out_size, void* d_ws, size_t ws_size,
                              hipStream_t stream)
{
    const float* x      = (const float*)d_in[0];
    const float* illu   = (const float*)d_in[1];
    const float* qkv_w  = (const float*)d_in[2];
    const float* qkv_b  = (const float*)d_in[3];
    const float* illu_w = (const float*)d_in[4];
    const float* illu_b = (const float*)d_in[5];
    const float* proj_w = (const float*)d_in[6];
    const float* proj_b = (const float*)d_in[7];
    float* out = (float*)d_out;

    ushort* Qx = (ushort*)d_ws;                     // 2MB (hi|lo)
    ushort* Kx = Qx + (size_t)NBH*HW*32;            // 2MB (hi|lo)
    ushort* Vt = Kx + (size_t)NBH*HW*32;            // 1MB [bh][d][key]
    float*  O  = (float*)(Vt + (size_t)NBH*HW*DH);  // 2MB fp32 [b][p][64]

    hipLaunchKernelGGL(qkv_kernel, dim3(1024), dim3(256), 0, stream,
                       x, illu, qkv_w, qkv_b, illu_w, illu_b, Qx, Kx, Vt);
    hipLaunchKernelGGL(attn_kernel, dim3(512), dim3(512), 0, stream,
                       Qx, Kx, Vt, O);
    hipLaunchKernelGGL(proj_kernel, dim3(1024), dim3(256), 0, stream,
                       O, proj_w, proj_b, out);
}